// Round 1
// baseline (620.906 us; speedup 1.0000x reference)
//
#include <hip/hip_runtime.h>

typedef unsigned short u16;
typedef unsigned int   u32;
typedef unsigned long long u64;

typedef __bf16 bf16x8 __attribute__((ext_vector_type(8)));
typedef float  f32x4  __attribute__((ext_vector_type(4)));
typedef u16    u16x4  __attribute__((ext_vector_type(4)));
typedef u16    u16x8  __attribute__((ext_vector_type(8)));

#define IN_F   4096
#define OUT_F  11008
#define TOKENS 4096

#define BM 128
#define BN 128
#define BK 32
#define MT (TOKENS / BM)   // 32
#define NT (OUT_F / BN)    // 86

// f32 -> bf16 round-to-nearest-even (exact for integers 0..255)
__device__ __forceinline__ u16 f2bf(float f) {
    u32 u = __float_as_uint(f);
    return (u16)((u + 0x7FFFu + ((u >> 16) & 1u)) >> 16);
}

// direct global->LDS async copy, 16B per lane; LDS dest is wave-uniform base + lane*16
#define GLOAD_LDS16(g, l)                                                        \
    __builtin_amdgcn_global_load_lds(                                            \
        (const __attribute__((address_space(1))) u32*)(u64)(g),                  \
        (__attribute__((address_space(3))) u32*)(u64)(l), 16, 0, 0)

// ---------------- prep_x: f32 -> bf16, plus per-row f32 sum ----------------
__global__ __launch_bounds__(256) void prep_x_kernel(
    const float* __restrict__ x, u16* __restrict__ xb, float* __restrict__ rowsum) {
    const int row = blockIdx.x;
    const int tid = threadIdx.x;
    const float4* xr = reinterpret_cast<const float4*>(x + (size_t)row * IN_F);
    u16x4* xo = reinterpret_cast<u16x4*>(xb + (size_t)row * IN_F);
    float s = 0.f;
#pragma unroll
    for (int i = 0; i < 4; ++i) {
        float4 v = xr[tid * 4 + i];
        s += v.x + v.y + v.z + v.w;
        u16x4 o;
        o[0] = f2bf(v.x); o[1] = f2bf(v.y); o[2] = f2bf(v.z); o[3] = f2bf(v.w);
        xo[tid * 4 + i] = o;
    }
#pragma unroll
    for (int off = 32; off > 0; off >>= 1) s += __shfl_down(s, off, 64);
    __shared__ float ws[4];
    if ((tid & 63) == 0) ws[tid >> 6] = s;
    __syncthreads();
    if (tid == 0) rowsum[row] = ws[0] + ws[1] + ws[2] + ws[3];
}

// ---------------- prep_w: int32 (0..255) -> bf16 (exact) ----------------
__global__ __launch_bounds__(256) void prep_w_kernel(
    const int* __restrict__ wq, u16* __restrict__ wb) {
    const size_t total8 = (size_t)OUT_F * IN_F / 8;
    size_t i = (size_t)blockIdx.x * blockDim.x + threadIdx.x;
    const size_t stride = (size_t)gridDim.x * blockDim.x;
    const int4* p = reinterpret_cast<const int4*>(wq);
    u16x8* o = reinterpret_cast<u16x8*>(wb);
    for (; i < total8; i += stride) {
        int4 a = p[i * 2];
        int4 b = p[i * 2 + 1];
        u16x8 v;
        v[0] = f2bf((float)a.x); v[1] = f2bf((float)a.y);
        v[2] = f2bf((float)a.z); v[3] = f2bf((float)a.w);
        v[4] = f2bf((float)b.x); v[5] = f2bf((float)b.y);
        v[6] = f2bf((float)b.z); v[7] = f2bf((float)b.w);
        o[i] = v;
    }
}

// ---------------- qgemm: bf16 MFMA GEMM + fused dequant epilogue ----------------
// C[t,o] = scale[o] * (sum_k Xb[t,k]*Wb[o,k] - zero[o]*rowsum[t]) + bias[o]
__global__ __launch_bounds__(256) void qgemm_kernel(
    const u16* __restrict__ Xb, const u16* __restrict__ Wb,
    const float* __restrict__ rowsum, const float* __restrict__ scale,
    const float* __restrict__ zero, const float* __restrict__ bias,
    float* __restrict__ out) {
    __shared__ u16 As[BM * BK];  // 8 KB, [row][k] row-major, k contiguous
    __shared__ u16 Bs[BN * BK];  // 8 KB

    // bijective XCD swizzle (grid = 2752, divisible by 8)
    int bid = blockIdx.x;
    const int cpx = (MT * NT) / 8;
    bid = (bid % 8) * cpx + bid / 8;
    const int mt = bid / NT;
    const int nt = bid % NT;

    const int tid  = threadIdx.x;
    const int w    = tid >> 6;        // wave 0..3
    const int lane = tid & 63;
    const int wr   = w >> 1;          // wave row 0..1 (64-row half)
    const int wc   = w & 1;           // wave col 0..1 (64-col half)
    const int l15  = lane & 15;
    const int kq   = lane >> 4;       // 0..3

    const size_t abase = (size_t)mt * BM * IN_F;
    const size_t bbase = (size_t)nt * BN * IN_F;

    // staging role: chunk c = w*2+i covers LDS bytes [c*1024, c*1024+1024)
    // byte off = c*1024 + lane*16 ; row = off/64 ; elem-in-row = (off%64)/2
    const int c0   = w * 2;
    const int off0 = c0 * 1024 + lane * 16;
    const int row0s = off0 >> 6;
    const int ke0   = (off0 & 63) >> 1;   // element offset within row (0,8,16,24)

    f32x4 acc[4][4];
    const f32x4 zf = {0.f, 0.f, 0.f, 0.f};
#pragma unroll
    for (int m = 0; m < 4; ++m)
#pragma unroll
        for (int n = 0; n < 4; ++n) acc[m][n] = zf;

    for (int kt = 0; kt < IN_F / BK; ++kt) {
        __syncthreads();  // previous iter's LDS reads complete before overwrite
        const size_t koff = (size_t)kt * BK;
#pragma unroll
        for (int i = 0; i < 2; ++i) {
            const int c   = c0 + i;
            const int row = row0s + i * 16;  // +1024 bytes = +16 rows
            const u16* ga = Xb + abase + (size_t)row * IN_F + koff + ke0;
            GLOAD_LDS16(ga, (char*)As + c * 1024);
            const u16* gb = Wb + bbase + (size_t)row * IN_F + koff + ke0;
            GLOAD_LDS16(gb, (char*)Bs + c * 1024);
        }
        __syncthreads();  // staging visible (implicit vmcnt(0) drain)

        bf16x8 a[4], b[4];
#pragma unroll
        for (int m = 0; m < 4; ++m)
            a[m] = *reinterpret_cast<const bf16x8*>(&As[(wr * 64 + m * 16 + l15) * BK + kq * 8]);
#pragma unroll
        for (int n = 0; n < 4; ++n)
            b[n] = *reinterpret_cast<const bf16x8*>(&Bs[(wc * 64 + n * 16 + l15) * BK + kq * 8]);
#pragma unroll
        for (int m = 0; m < 4; ++m)
#pragma unroll
            for (int n = 0; n < 4; ++n)
                acc[m][n] = __builtin_amdgcn_mfma_f32_16x16x32_bf16(a[m], b[n], acc[m][n], 0, 0, 0);
    }

    // epilogue: C/D layout col = lane&15, row = (lane>>4)*4 + j  [m89-verified]
    const int rowt = mt * BM + wr * 64;
    const int colt = nt * BN + wc * 64;

    float rs[4][4];
#pragma unroll
    for (int m = 0; m < 4; ++m)
#pragma unroll
        for (int j = 0; j < 4; ++j)
            rs[m][j] = rowsum[rowt + m * 16 + kq * 4 + j];

#pragma unroll
    for (int n = 0; n < 4; ++n) {
        const int col = colt + n * 16 + l15;
        const float sc = scale[col];
        const float zp = zero[col];
        const float bs = bias[col];
#pragma unroll
        for (int m = 0; m < 4; ++m) {
            const int rb = rowt + m * 16 + kq * 4;
#pragma unroll
            for (int j = 0; j < 4; ++j) {
                out[(size_t)(rb + j) * OUT_F + col] =
                    sc * (acc[m][n][j] - zp * rs[m][j]) + bs;
            }
        }
    }
}

extern "C" void kernel_launch(void* const* d_in, const int* in_sizes, int n_in,
                              void* d_out, int out_size, void* d_ws, size_t ws_size,
                              hipStream_t stream) {
    const float* x     = (const float*)d_in[0];
    const int*   wq    = (const int*)d_in[1];
    const float* scale = (const float*)d_in[2];
    const float* zero  = (const float*)d_in[3];
    const float* bias  = (const float*)d_in[4];
    float* out = (float*)d_out;

    // workspace layout: Wb (90.2 MB) | Xb (33.6 MB) | rowsum (16 KB)  => ~124 MB
    char* ws = (char*)d_ws;
    u16* Wb = (u16*)ws;
    u16* Xb = (u16*)(ws + (size_t)OUT_F * IN_F * 2);
    float* rowsum = (float*)(ws + (size_t)OUT_F * IN_F * 2 + (size_t)TOKENS * IN_F * 2);

    prep_w_kernel<<<2048, 256, 0, stream>>>(wq, Wb);
    prep_x_kernel<<<TOKENS, 256, 0, stream>>>(x, Xb, rowsum);
    qgemm_kernel<<<MT * NT, 256, 0, stream>>>(Xb, Wb, rowsum, scale, zero, bias, out);
}

// Round 2
// 390.190 us; speedup vs baseline: 1.5913x; 1.5913x over previous
//
#include <hip/hip_runtime.h>

typedef unsigned short u16;
typedef unsigned int   u32;
typedef unsigned long long u64;

typedef __bf16 bf16x8 __attribute__((ext_vector_type(8)));
typedef float  f32x4  __attribute__((ext_vector_type(4)));
typedef u16    u16x4  __attribute__((ext_vector_type(4)));
typedef u16    u16x8  __attribute__((ext_vector_type(8)));

#define IN_F   4096
#define OUT_F  11008
#define TOKENS 4096

#define BM 256
#define BN 256
#define BK 64
#define MT (TOKENS / BM)   // 16
#define NT (OUT_F / BN)    // 43
#define KTILES (IN_F / BK) // 64

// f32 -> bf16 round-to-nearest-even (exact for integers 0..255)
__device__ __forceinline__ u16 f2bf(float f) {
    u32 u = __float_as_uint(f);
    return (u16)((u + 0x7FFFu + ((u >> 16) & 1u)) >> 16);
}

// direct global->LDS async copy, 16B per lane; LDS dest = wave-uniform base + lane*16
#define GLOAD_LDS16(g, l)                                                        \
    __builtin_amdgcn_global_load_lds(                                            \
        (const __attribute__((address_space(1))) u32*)(u64)(g),                  \
        (__attribute__((address_space(3))) u32*)(u64)(l), 16, 0, 0)

#define BAR() __builtin_amdgcn_s_barrier()
#define VM(N) asm volatile("s_waitcnt vmcnt(" #N ")" ::: "memory")

// ---------------- prep_x: f32 -> bf16, plus per-row f32 sum ----------------
__global__ __launch_bounds__(256) void prep_x_kernel(
    const float* __restrict__ x, u16* __restrict__ xb, float* __restrict__ rowsum) {
    const int row = blockIdx.x;
    const int tid = threadIdx.x;
    const float4* xr = reinterpret_cast<const float4*>(x + (size_t)row * IN_F);
    u16x4* xo = reinterpret_cast<u16x4*>(xb + (size_t)row * IN_F);
    float s = 0.f;
#pragma unroll
    for (int i = 0; i < 4; ++i) {
        float4 v = xr[tid * 4 + i];
        s += v.x + v.y + v.z + v.w;
        u16x4 o;
        o[0] = f2bf(v.x); o[1] = f2bf(v.y); o[2] = f2bf(v.z); o[3] = f2bf(v.w);
        xo[tid * 4 + i] = o;
    }
#pragma unroll
    for (int off = 32; off > 0; off >>= 1) s += __shfl_down(s, off, 64);
    __shared__ float wsum[4];
    if ((tid & 63) == 0) wsum[tid >> 6] = s;
    __syncthreads();
    if (tid == 0) rowsum[row] = wsum[0] + wsum[1] + wsum[2] + wsum[3];
}

// ---------------- prep_w: int32 (0..255) -> bf16 (exact) ----------------
__global__ __launch_bounds__(256) void prep_w_kernel(
    const int* __restrict__ wq, u16* __restrict__ wb) {
    const size_t total8 = (size_t)OUT_F * IN_F / 8;
    size_t i = (size_t)blockIdx.x * blockDim.x + threadIdx.x;
    const size_t stride = (size_t)gridDim.x * blockDim.x;
    const int4* p = reinterpret_cast<const int4*>(wq);
    u16x8* o = reinterpret_cast<u16x8*>(wb);
    for (; i < total8; i += stride) {
        int4 a = p[i * 2];
        int4 b = p[i * 2 + 1];
        u16x8 v;
        v[0] = f2bf((float)a.x); v[1] = f2bf((float)a.y);
        v[2] = f2bf((float)a.z); v[3] = f2bf((float)a.w);
        v[4] = f2bf((float)b.x); v[5] = f2bf((float)b.y);
        v[6] = f2bf((float)b.z); v[7] = f2bf((float)b.w);
        o[i] = v;
    }
}

// ---------------- qgemm: 256x256 8-phase bf16 MFMA GEMM + dequant epilogue --------
// C[t,o] = scale[o] * (sum_k Xb[t,k]*Wb[o,k] - zero[o]*rowsum[t]) + bias[o]
//
// LDS tile layout: row-major [256][64] bf16 (128B rows), XOR-swizzle
// byte ^= ((row&7)<<4) applied on the READ side and (inverse == same) on the
// pre-swizzled GLOBAL SOURCE; global_load_lds writes linearly (rule 21).
//
// Region schedule (steady iteration, tiles t=even in buf0, t+1 in buf1):
//   P1 reads Ah0,Bh0(t)  stages Ah1(t+1)->buf1   vmcnt(10) at end
//   P2 reads Bh1(t)      stages Ah0(t+2)->buf0   vmcnt(10)
//   P3 reads Ah1(t)      stages Bh0(t+2)->buf0   --
//   P4 reads --          stages Bh1(t+2)->buf0   vmcnt(10)
//   P5 reads Ah0,Bh0(t+1) stages Ah1(t+2)->buf0  vmcnt(10)
//   P6 reads Bh1(t+1)    stages Ah0(t+3)->buf1   vmcnt(10)
//   P7 reads Ah1(t+1)    stages Bh0(t+3)->buf1   --
//   P8 reads --          stages Bh1(t+3)->buf1   vmcnt(10)
// Ah0 = rows {0-63,128-191}, Ah1 = rows {64-127,192-255} (per-wave m-halves)
// Bh0 = rows {0-31,64-95,128-159,192-223}, Bh1 = complement (per-wave n-halves)
// Every region is staged 5 phases before its protecting vmcnt; vmcnt(10) =
// 5 half-regions x 2 loads/thread outstanding. Waits precede a barrier, so
// all waves' loads for a region are complete before any wave reads it.

// A-frag half load: af[m][s] for m-half MH
#define LDA_HALF(P, MH)                                                           \
    _Pragma("unroll") for (int m = 0; m < 4; ++m)                                 \
    _Pragma("unroll") for (int s = 0; s < 2; ++s)                                 \
        af[m][s] = *(const bf16x8*)((const char*)&AS[P][0] +                      \
            ((wr * 128 + (MH) * 64 + m * 16 + l15) * 128 +                        \
             (((s * 4 + kq) ^ (l15 & 7)) << 4)));

// B-frag half load: bfr[NH*2+n][s]
#define LDB_HALF(P, NH)                                                           \
    _Pragma("unroll") for (int n = 0; n < 2; ++n)                                 \
    _Pragma("unroll") for (int s = 0; s < 2; ++s)                                 \
        bfr[(NH) * 2 + n][s] = *(const bf16x8*)((const char*)&BS[P][0] +          \
            ((wc * 64 + (NH) * 32 + n * 16 + l15) * 128 +                         \
             (((s * 4 + kq) ^ (l15 & 7)) << 4)));

#define MFMA_Q(MH, NH)                                                            \
    __builtin_amdgcn_s_setprio(1);                                                \
    _Pragma("unroll") for (int m = 0; m < 4; ++m)                                 \
    _Pragma("unroll") for (int n = 0; n < 2; ++n)                                 \
    _Pragma("unroll") for (int s = 0; s < 2; ++s)                                 \
        acc[(MH) * 4 + m][(NH) * 2 + n] = __builtin_amdgcn_mfma_f32_16x16x32_bf16(\
            af[m][s], bfr[(NH) * 2 + n][s], acc[(MH) * 4 + m][(NH) * 2 + n],      \
            0, 0, 0);                                                             \
    __builtin_amdgcn_s_setprio(0);

// Stage one A half-region H of k-tile KT into buf P (2 x 1KB chunks per wave).
// chunk list for half H: kb = H*8 + (i&7) + (i>=8)*16, i = 2w+j.
#define STAGE_A(P, H, KT) {                                                       \
    _Pragma("unroll") for (int j = 0; j < 2; ++j) {                               \
        const int i_ = 2 * w + j;                                                 \
        const int chunk = (((H) * 8 + (i_ & 7) + ((i_ >> 3) << 4)) << 10);        \
        const int row_ = (chunk + lane * 16) >> 7;                                \
        const int cb_ = (((lane & 7) ^ (row_ & 7)) << 4);                         \
        const u16* g_ = Abase + (size_t)row_ * IN_F + (KT) * BK + (cb_ >> 1);     \
        GLOAD_LDS16(g_, (char*)&AS[P][0] + chunk);                                \
    } }

// B half-region H: kb = H*4 + (i&3) + (i>>2)*8
#define STAGE_B(P, H, KT) {                                                       \
    _Pragma("unroll") for (int j = 0; j < 2; ++j) {                               \
        const int i_ = 2 * w + j;                                                 \
        const int chunk = (((H) * 4 + (i_ & 3) + ((i_ >> 2) << 3)) << 10);        \
        const int row_ = (chunk + lane * 16) >> 7;                                \
        const int cb_ = (((lane & 7) ^ (row_ & 7)) << 4);                         \
        const u16* g_ = Bbase + (size_t)row_ * IN_F + (KT) * BK + (cb_ >> 1);     \
        GLOAD_LDS16(g_, (char*)&BS[P][0] + chunk);                                \
    } }

__global__ __launch_bounds__(512, 2) void qgemm_kernel(
    const u16* __restrict__ Xb, const u16* __restrict__ Wb,
    const float* __restrict__ rowsum, const float* __restrict__ scale,
    const float* __restrict__ zero, const float* __restrict__ bias,
    float* __restrict__ out) {
    __shared__ u16 AS[2][BM * BK];  // 2 x 32KB
    __shared__ u16 BS[2][BN * BK];  // 2 x 32KB

    // bijective XCD swizzle (grid = 688, divisible by 8)
    int bid = blockIdx.x;
    bid = (bid & 7) * (MT * NT / 8) + (bid >> 3);
    const int mt = bid / NT;
    const int nt = bid % NT;

    const int tid  = threadIdx.x;
    const int w    = tid >> 6;        // wave 0..7
    const int lane = tid & 63;
    const int wr   = w >> 2;          // wave row-half 0..1 (128 rows each)
    const int wc   = w & 3;           // wave col 0..3 (64 cols each)
    const int l15  = lane & 15;
    const int kq   = lane >> 4;       // 0..3

    const u16* Abase = Xb + (size_t)mt * BM * IN_F;
    const u16* Bbase = Wb + (size_t)nt * BN * IN_F;

    bf16x8 af[4][2];
    bf16x8 bfr[4][2];
    f32x4 acc[8][4];
    const f32x4 zf = {0.f, 0.f, 0.f, 0.f};
#pragma unroll
    for (int m = 0; m < 8; ++m)
#pragma unroll
        for (int n = 0; n < 4; ++n) acc[m][n] = zf;

    // ---- prologue: 7 half-stages in steady-state FIFO order ----
    STAGE_A(0, 0, 0);   // Ah0(0)
    STAGE_B(0, 0, 0);   // Bh0(0)
    STAGE_B(0, 1, 0);   // Bh1(0)
    STAGE_A(0, 1, 0);   // Ah1(0)
    STAGE_A(1, 0, 1);   // Ah0(1)
    STAGE_B(1, 0, 1);   // Bh0(1)
    STAGE_B(1, 1, 1);   // Bh1(1)
    VM(10);             // Ah0(0), Bh0(0) landed (and more)
    BAR();

    // ---- steady loop: 31 iterations, tiles 0..61 ----
    for (int i = 0; i < 31; ++i) {
        const int t = 2 * i;
        // P1
        LDA_HALF(0, 0); LDB_HALF(0, 0);
        STAGE_A(1, 1, t + 1);
        BAR();
        MFMA_Q(0, 0);
        VM(10); BAR();
        // P2
        LDB_HALF(0, 1);
        STAGE_A(0, 0, t + 2);
        BAR();
        MFMA_Q(0, 1);
        VM(10); BAR();
        // P3
        LDA_HALF(0, 1);
        STAGE_B(0, 0, t + 2);
        BAR();
        MFMA_Q(1, 0);
        BAR();
        // P4
        STAGE_B(0, 1, t + 2);
        BAR();
        MFMA_Q(1, 1);
        VM(10); BAR();
        // P5
        LDA_HALF(1, 0); LDB_HALF(1, 0);
        STAGE_A(0, 1, t + 2);
        BAR();
        MFMA_Q(0, 0);
        VM(10); BAR();
        // P6
        LDB_HALF(1, 1);
        STAGE_A(1, 0, t + 3);
        BAR();
        MFMA_Q(0, 1);
        VM(10); BAR();
        // P7
        LDA_HALF(1, 1);
        STAGE_B(1, 0, t + 3);
        BAR();
        MFMA_Q(1, 0);
        BAR();
        // P8
        STAGE_B(1, 1, t + 3);
        BAR();
        MFMA_Q(1, 1);
        VM(10); BAR();
    }

    // ---- peeled final iteration: tiles 62, 63 ----
    // P1
    LDA_HALF(0, 0); LDB_HALF(0, 0);
    STAGE_A(1, 1, 63);
    BAR();
    MFMA_Q(0, 0);
    VM(10); BAR();
    // P2
    LDB_HALF(0, 1);
    BAR();
    MFMA_Q(0, 1);
    VM(8); BAR();
    // P3
    LDA_HALF(0, 1);
    BAR();
    MFMA_Q(1, 0);
    BAR();
    // P4
    BAR();
    MFMA_Q(1, 1);
    VM(4); BAR();
    // P5
    LDA_HALF(1, 0); LDB_HALF(1, 0);
    BAR();
    MFMA_Q(0, 0);
    VM(2); BAR();
    // P6
    LDB_HALF(1, 1);
    BAR();
    MFMA_Q(0, 1);
    VM(0); BAR();
    // P7
    LDA_HALF(1, 1);
    BAR();
    MFMA_Q(1, 0);
    BAR();
    // P8
    BAR();
    MFMA_Q(1, 1);

    // ---- epilogue: C/D layout col = lane&15, row = (lane>>4)*4 + j ----
    const int rowt = mt * BM + wr * 128;
    const int colt = nt * BN + wc * 64;

    float rs[8][4];
#pragma unroll
    for (int m = 0; m < 8; ++m)
#pragma unroll
        for (int j = 0; j < 4; ++j)
            rs[m][j] = rowsum[rowt + m * 16 + kq * 4 + j];

#pragma unroll
    for (int n = 0; n < 4; ++n) {
        const int col = colt + n * 16 + l15;
        const float sc = scale[col];
        const float zp = zero[col];
        const float bs = bias[col];
#pragma unroll
        for (int m = 0; m < 8; ++m) {
            const int rb = rowt + m * 16 + kq * 4;
#pragma unroll
            for (int j = 0; j < 4; ++j) {
                out[(size_t)(rb + j) * OUT_F + col] =
                    sc * (acc[m][n][j] - zp * rs[m][j]) + bs;
            }
        }
    }
}

extern "C" void kernel_launch(void* const* d_in, const int* in_sizes, int n_in,
                              void* d_out, int out_size, void* d_ws, size_t ws_size,
                              hipStream_t stream) {
    const float* x     = (const float*)d_in[0];
    const int*   wq    = (const int*)d_in[1];
    const float* scale = (const float*)d_in[2];
    const float* zero  = (const float*)d_in[3];
    const float* bias  = (const float*)d_in[4];
    float* out = (float*)d_out;

    // workspace layout: Wb (90.2 MB) | Xb (33.6 MB) | rowsum (16 KB)
    char* ws = (char*)d_ws;
    u16* Wb = (u16*)ws;
    u16* Xb = (u16*)(ws + (size_t)OUT_F * IN_F * 2);
    float* rowsum = (float*)(ws + (size_t)OUT_F * IN_F * 2 + (size_t)TOKENS * IN_F * 2);

    prep_w_kernel<<<2048, 256, 0, stream>>>(wq, Wb);
    prep_x_kernel<<<TOKENS, 256, 0, stream>>>(x, Xb, rowsum);
    qgemm_kernel<<<MT * NT, 512, 0, stream>>>(Xb, Wb, rowsum, scale, zero, bias, out);
}